// Round 13
// baseline (51.814 us; speedup 1.0000x reference)
//
#include <hip/hip_runtime.h>
#include <hip/hip_bf16.h>

typedef __attribute__((ext_vector_type(8))) short short8;
typedef __attribute__((ext_vector_type(4))) short s16x4;
typedef __attribute__((ext_vector_type(4))) float f32x4;

#define NB_H 96
#define NB_W 128
#define NB_D 32
#define NB_C 16
#define NB_F 16
#define NPIX (2 * NB_H * NB_W)                 // 24576
#define KB2_U16 (14 * 512)                     // 7168 u16 = 14336 B
#define WS_NEED ((size_t)KB2_U16 * 2)
#define SLAB_STRIDE 1280                       // 32 rows * 40 B
#define NSLAB 36                               // 6-row x 6-col circular window
#define DV_OFF (NSLAB * SLAB_STRIDE)           // 46080
#define LDS_BYTES (DV_OFF + 64)                // 46144

// fp32 -> bf16 RNE
static __device__ __forceinline__ short fcvt(float f) {
  return (short)__builtin_bit_cast(unsigned short, __float2bfloat16(f));
}

// Pair table: p=3q+m (q=0..3): m=0 -> taps(6q,6q+1) [UNIF n=2q, kd=0/1];
// m=1 -> (6q+3,6q+4) [UNIF n=2q+1]; m=2 -> (6q+2,6q+5) [MIX kd=2].
// p=12 -> (24,25) [UNIF n=8]. p=13 -> (26,pad). tap t = n*3+kd.

// ---- weights prep: kern fp32 -> bf16 B-frag layout [p][grp][f][j] ---------
__global__ __launch_bounds__(256) void sconv3d_wprep(
    const float* __restrict__ kern, unsigned short* __restrict__ kb2) {
  const int i = blockIdx.x * 256 + threadIdx.x;
  if (i >= KB2_U16) return;
  const int p = i >> 9;
  const int g = (i >> 7) & 3;
  const int f = (i >> 3) & 15;
  const int j = i & 7;
  const int k = g * 8 + j;
  int lo, hi;
  if (p < 12) {
    const int q = p / 3, m = p % 3;
    lo = (m == 0) ? 6 * q : (m == 1) ? 6 * q + 3 : 6 * q + 2;
    hi = (m == 0) ? 6 * q + 1 : (m == 1) ? 6 * q + 4 : 6 * q + 5;
  } else if (p == 12) { lo = 24; hi = 25; }
  else { lo = 26; hi = -1; }
  const int t = (k < 16) ? lo : hi;
  const int c = k & 15;
  kb2[i] = (t >= 0) ? (unsigned short)fcvt(kern[(t * 16 + c) * 16 + f])
                    : (unsigned short)0;
}

// ---- main: rolling 6-row window, 4w x 12h chunk, 2 px/wave/step -----------
__global__ __launch_bounds__(256, 2) void sconv3d_roll(
    const float* __restrict__ img, const int* __restrict__ bp,
    const unsigned short* __restrict__ kb2, const float* __restrict__ dvp,
    float* __restrict__ out) {
  __shared__ char Sb[LDS_BYTES];
  const int tid = threadIdx.x;
  const int lane = tid & 63;
  const int r = lane & 15;          // A: d row; B/D: f column
  const int grp = lane >> 4;        // 0..3
  const int vc = (grp & 1) * 16;    // byte offset of c-slice within 32B row
  const int halfbit = grp >> 1;     // K half: 0 -> tap lo, 1 -> tap hi
  const int rA = r + halfbit - 1;   // depth row pre-rel, kd=(0,1) pairs
  const int rX = r + 1;             // depth row pre-rel, kd=2 pairs
  const int voff_dv = DV_OFF + vc;

  // B-frags, held in registers for the whole kernel
  short8 bfrag[14];
#pragma unroll
  for (int p = 0; p < 14; ++p)
    bfrag[p] = *(const short8*)(kb2 + p * 512 + grp * 128 + r * 8);

  // chunk decode, XCD-chunked bijective swizzle: 512 = 8 * 64
  const int bid = (blockIdx.x & 7) * 64 + (blockIdx.x >> 3);
  const int b = bid >= 256;                   // 256 chunks per batch
  const int rem = bid - b * 256;
  const int h0 = (rem >> 5) * 12;             // 8 h-chunks
  const int w0 = (rem & 31) * 4;              // 32 w-chunks

  // staging thread mapping
  const int sg = tid >> 7;                    // 0..1
  const int t2 = tid & 127;
  const int drow = t2 >> 2;                   // d row 0..31
  const int sq8 = (t2 & 3) * 8;               // byte offset in 32B row

  // ---- prologue: stage rows h0-1 .. h0+2 (24 slabs) ----
#pragma unroll
  for (int k = 0; k < 12; ++k) {
    const int r2 = 2 * k + sg;                // 0..23
    const int row = r2 / 6;                   // 0..3 (k literal -> folds)
    const int col = r2 - 6 * row;             // 0..5
    const int hr = h0 - 1 + row;
    const int hh = min(max(hr, 0), NB_H - 1);
    const int ww = min(max(w0 + col - 1, 0), NB_W - 1);
    const float4 v = *(const float4*)(
        img + ((b * NB_H + hh) * NB_W + ww) * (NB_D * NB_C) + t2 * 4);
    s16x4 o;
    o[0] = fcvt(v.x); o[1] = fcvt(v.y); o[2] = fcvt(v.z); o[3] = fcvt(v.w);
    const int slot = (hr - h0 + 1) % 6;       // in [0,3]
    *(s16x4*)(Sb + (slot * 6 + col) * SLAB_STRIDE + drow * 40 + sq8) = o;
  }
  if (tid < 16) ((unsigned short*)(Sb + DV_OFF))[tid] =
      (unsigned short)fcvt(dvp[0]);

  const int wid = __builtin_amdgcn_readfirstlane((int)(tid >> 6));  // 0..3
  const int w = w0 + wid;

#pragma unroll
  for (int p = 0; p < 14; ++p)
    asm volatile("" : "+v"(bfrag[p]));

  __syncthreads();

#pragma unroll 1
  for (int j = 0; j < 6; ++j) {
    const int h = h0 + 2 * j;

    // ---- 1) issue stage loads for rows h+3, h+4 (12 slabs) ----
    float4 stv[6];
    int stb[6];
    if (j < 5) {
#pragma unroll
      for (int k = 0; k < 6; ++k) {
        const int r2 = 2 * k + sg;            // 0..11
        const int row = (r2 >= 6) ? 1 : 0;
        const int col = r2 - 6 * row;
        const int hr = h + 3 + row;
        const int hh = min(hr, NB_H - 1);
        const int ww = min(max(w0 + col - 1, 0), NB_W - 1);
        stv[k] = *(const float4*)(
            img + ((b * NB_H + hh) * NB_W + ww) * (NB_D * NB_C) + t2 * 4);
        stb[k] = (((hr - h0 + 1) % 6) * 6 + col) * SLAB_STRIDE +
                 drow * 40 + sq8;
      }
    }

    // ---- 2) per-step decode: pixels (h, w) and (h+1, w) ----
    const int pixA = (b * NB_H + h) * NB_W + w;
    const int pixB = pixA + NB_W;
    const int bpcA = bp[pixA];
    const int bpcB = bp[pixB];

#define CALCN(HROW, BPC, DI, DJ, SV, BA, RE)                            \
  {                                                                     \
    const int hh = (HROW) + (DI), ww = w + (DJ);                        \
    SV = (hh >= 0) & (hh < NB_H) & (ww >= 0) & (ww < NB_W);             \
    const int hc = min(max(hh, 0), NB_H - 1);                           \
    const int wc = min(max(ww, 0), NB_W - 1);                           \
    RE = (BPC)-bp[(b * NB_H + hc) * NB_W + wc];                         \
    BA = ((((HROW)-h0 + (DI) + 1) % 6) * 6 + wid + (DJ) + 1) *          \
         SLAB_STRIDE;                                                   \
  }

    int Asv0, Aba0, Are0, Asv1, Aba1, Are1, Asv2, Aba2, Are2;
    int Asv3, Aba3, Are3, Asv4, Aba4, Are4, Asv5, Aba5, Are5;
    int Asv6, Aba6, Are6, Asv7, Aba7, Are7, Asv8, Aba8, Are8;
    int Bsv0, Bba0, Bre0, Bsv1, Bba1, Bre1, Bsv2, Bba2, Bre2;
    int Bsv3, Bba3, Bre3, Bsv4, Bba4, Bre4, Bsv5, Bba5, Bre5;
    int Bsv6, Bba6, Bre6, Bsv7, Bba7, Bre7, Bsv8, Bba8, Bre8;
    CALCN(h, bpcA, -1, -1, Asv0, Aba0, Are0);
    CALCN(h, bpcA, -1, 0, Asv1, Aba1, Are1);
    CALCN(h, bpcA, -1, 1, Asv2, Aba2, Are2);
    CALCN(h, bpcA, 0, -1, Asv3, Aba3, Are3);
    CALCN(h, bpcA, 0, 0, Asv4, Aba4, Are4);
    CALCN(h, bpcA, 0, 1, Asv5, Aba5, Are5);
    CALCN(h, bpcA, 1, -1, Asv6, Aba6, Are6);
    CALCN(h, bpcA, 1, 0, Asv7, Aba7, Are7);
    CALCN(h, bpcA, 1, 1, Asv8, Aba8, Are8);
    CALCN(h + 1, bpcB, -1, -1, Bsv0, Bba0, Bre0);
    CALCN(h + 1, bpcB, -1, 0, Bsv1, Bba1, Bre1);
    CALCN(h + 1, bpcB, -1, 1, Bsv2, Bba2, Bre2);
    CALCN(h + 1, bpcB, 0, -1, Bsv3, Bba3, Bre3);
    CALCN(h + 1, bpcB, 0, 0, Bsv4, Bba4, Bre4);
    CALCN(h + 1, bpcB, 0, 1, Bsv5, Bba5, Bre5);
    CALCN(h + 1, bpcB, 1, -1, Bsv6, Bba6, Bre6);
    CALCN(h + 1, bpcB, 1, 0, Bsv7, Bba7, Bre7);
    CALCN(h + 1, bpcB, 1, 1, Bsv8, Bba8, Bre8);
#undef CALCN

    f32x4 accA0 = {0.f, 0.f, 0.f, 0.f}, accA1 = {0.f, 0.f, 0.f, 0.f};
    f32x4 accB0 = {0.f, 0.f, 0.f, 0.f}, accB1 = {0.f, 0.f, 0.f, 0.f};

    short8 Xa0, Xa1, Xb0, Xb1, Ya0, Ya1, Yb0, Yb1;

#define LOADQ(S, DS0A, BAA, SVA, DS0B, BAB, SVB)                        \
  {                                                                     \
    int d_, o_;                                                         \
    d_ = (DS0A);      o_ = (BAA) + d_ * 40 + vc;                        \
    o_ = ((SVA) && (unsigned)d_ < NB_D) ? o_ : voff_dv;                 \
    S##a0 = *(const short8*)(Sb + o_);                                  \
    d_ = (DS0A) + 16; o_ = (BAA) + d_ * 40 + vc;                        \
    o_ = ((SVA) && (unsigned)d_ < NB_D) ? o_ : voff_dv;                 \
    S##a1 = *(const short8*)(Sb + o_);                                  \
    d_ = (DS0B);      o_ = (BAB) + d_ * 40 + vc;                        \
    o_ = ((SVB) && (unsigned)d_ < NB_D) ? o_ : voff_dv;                 \
    S##b0 = *(const short8*)(Sb + o_);                                  \
    d_ = (DS0B) + 16; o_ = (BAB) + d_ * 40 + vc;                        \
    o_ = ((SVB) && (unsigned)d_ < NB_D) ? o_ : voff_dv;                 \
    S##b1 = *(const short8*)(Sb + o_);                                  \
  }

#define LOAD_U(S, N) \
  LOADQ(S, rA + Are##N, Aba##N, Asv##N, rA + Bre##N, Bba##N, Bsv##N)

#define LOAD_M(S, NE, NO)                                               \
  {                                                                     \
    const int asv = halfbit ? Asv##NO : Asv##NE;                        \
    const int aba = halfbit ? Aba##NO : Aba##NE;                        \
    const int are = halfbit ? Are##NO : Are##NE;                        \
    const int bsv = halfbit ? Bsv##NO : Bsv##NE;                        \
    const int bba = halfbit ? Bba##NO : Bba##NE;                        \
    const int bre = halfbit ? Bre##NO : Bre##NE;                        \
    LOADQ(S, rX + are, aba, asv, rX + bre, bba, bsv)                    \
  }

#define LOAD_M13(S, NE)                                                 \
  {                                                                     \
    const int asv = halfbit ? 0 : Asv##NE;                              \
    const int bsv = halfbit ? 0 : Bsv##NE;                              \
    LOADQ(S, rX + Are##NE, Aba##NE, asv, rX + Bre##NE, Bba##NE, bsv)    \
  }

#define FMA4(P, S)                                                      \
  {                                                                     \
    const short8 bf = bfrag[P];                                         \
    accA0 = __builtin_amdgcn_mfma_f32_16x16x32_bf16(S##a0, bf, accA0, 0, 0, 0); \
    accA1 = __builtin_amdgcn_mfma_f32_16x16x32_bf16(S##a1, bf, accA1, 0, 0, 0); \
    accB0 = __builtin_amdgcn_mfma_f32_16x16x32_bf16(S##b0, bf, accB0, 0, 0, 0); \
    accB1 = __builtin_amdgcn_mfma_f32_16x16x32_bf16(S##b1, bf, accB1, 0, 0, 0); \
  }

    LOAD_U(X, 0);                    // p0
    LOAD_U(Y, 1);                    // p1
    FMA4(0, X);  LOAD_M(X, 0, 1);    // p2
    FMA4(1, Y);  LOAD_U(Y, 2);       // p3
    FMA4(2, X);  LOAD_U(X, 3);       // p4
    FMA4(3, Y);  LOAD_M(Y, 2, 3);    // p5
    FMA4(4, X);  LOAD_U(X, 4);       // p6
    FMA4(5, Y);  LOAD_U(Y, 5);       // p7
    FMA4(6, X);  LOAD_M(X, 4, 5);    // p8
    FMA4(7, Y);  LOAD_U(Y, 6);       // p9
    FMA4(8, X);  LOAD_U(X, 7);       // p10
    FMA4(9, Y);  LOAD_M(Y, 6, 7);    // p11
    FMA4(10, X); LOAD_U(X, 8);       // p12
    FMA4(11, Y); LOAD_M13(Y, 8);     // p13
    FMA4(12, X);
    FMA4(13, Y);

#undef LOADQ
#undef LOAD_U
#undef LOAD_M
#undef LOAD_M13
#undef FMA4

    // ---- 4) output stores ----
    const int obaseA = pixA * (NB_D * NB_F);
    const int obaseB = pixB * (NB_D * NB_F);
#pragma unroll
    for (int rr = 0; rr < 4; ++rr) {
      out[obaseA + (grp * 4 + rr) * NB_F + r] = accA0[rr];
      out[obaseA + (grp * 4 + rr + 16) * NB_F + r] = accA1[rr];
      out[obaseB + (grp * 4 + rr) * NB_F + r] = accB0[rr];
      out[obaseB + (grp * 4 + rr + 16) * NB_F + r] = accB1[rr];
    }

    // ---- 5) drain staged loads, cvt, write to LDS ----
    if (j < 5) {
#pragma unroll
      for (int k = 0; k < 6; ++k) {
        s16x4 o;
        o[0] = fcvt(stv[k].x); o[1] = fcvt(stv[k].y);
        o[2] = fcvt(stv[k].z); o[3] = fcvt(stv[k].w);
        *(s16x4*)(Sb + stb[k]) = o;
      }
    }
    __syncthreads();
  }
}

// ---------------- fallback (self-contained) if ws is too small -------------
__global__ __launch_bounds__(256) void sconv3d_mfma(
    const float* __restrict__ img, const int* __restrict__ bp,
    const float* __restrict__ kern, const float* __restrict__ dvp,
    float* __restrict__ out, int npix) {
  __shared__ unsigned short Kb[28 * 256];
  const int tid = threadIdx.x;
  for (int idx = tid; idx < 28 * 256; idx += 256) {
    unsigned short v = 0;
    if (idx < 27 * 256) v = (unsigned short)fcvt(kern[idx]);
    Kb[idx] = v;
  }
  __syncthreads();

  const int lane = tid & 63;
  const int grp = lane >> 4;
  const int r = lane & 15;
  const int c0 = (grp & 1) * 8;
  const int half = grp >> 1;

  short8 bfrag[14];
#pragma unroll
  for (int p = 0; p < 14; ++p) {
#pragma unroll
    for (int j = 0; j < 8; ++j) {
      const int k = 8 * grp + j;
      const int t = 2 * p + (k >> 4);
      bfrag[p][j] = (short)Kb[t * 256 + (k & 15) * 16 + r];
    }
  }

  const int pix = blockIdx.x * 4 + (tid >> 6);
  if (pix >= npix) return;
  const int b = pix / (NB_H * NB_W);
  const int rem = pix - b * (NB_H * NB_W);
  const int h = rem >> 7;
  const int w = rem & (NB_W - 1);

  const float dv = dvp[0];
  const int bpc = bp[pix];

  f32x4 acc0 = {0.f, 0.f, 0.f, 0.f};
  f32x4 acc1 = {0.f, 0.f, 0.f, 0.f};

#pragma unroll
  for (int p = 0; p < 14; ++p) {
    const int t = 2 * p + half;
    const int n = t / 3;
    const int kd = t - 3 * n;
    const int i = n / 3;
    const int j = n - 3 * i;
    const int hh = h + i - 1;
    const int ww = w + j - 1;
    const bool sv =
        (t < 27) && (hh >= 0) && (hh < NB_H) && (ww >= 0) && (ww < NB_W);
    const int hc = min(max(hh, 0), NB_H - 1);
    const int wc = min(max(ww, 0), NB_W - 1);
    const int nidx = (b * NB_H + hc) * NB_W + wc;
    const int rel = bpc - bp[nidx];
    const int base = nidx * (NB_D * NB_C);
    const int dsh = (kd - 1) + rel;

    const int ds0 = r + dsh;
    short8 a0;
    {
      float va[8];
      if (sv && (ds0 >= 0) && (ds0 < NB_D)) {
        const float4* pp = (const float4*)(img + base + ds0 * NB_C + c0);
        const float4 x = pp[0];
        const float4 y = pp[1];
        va[0] = x.x; va[1] = x.y; va[2] = x.z; va[3] = x.w;
        va[4] = y.x; va[5] = y.y; va[6] = y.z; va[7] = y.w;
      } else {
#pragma unroll
        for (int q = 0; q < 8; ++q) va[q] = dv;
      }
#pragma unroll
      for (int q = 0; q < 8; ++q) a0[q] = fcvt(va[q]);
    }
    acc0 = __builtin_amdgcn_mfma_f32_16x16x32_bf16(a0, bfrag[p], acc0, 0, 0, 0);

    const int ds1 = ds0 + 16;
    short8 a1;
    {
      float va[8];
      if (sv && (ds1 >= 0) && (ds1 < NB_D)) {
        const float4* pp = (const float4*)(img + base + ds1 * NB_C + c0);
        const float4 x = pp[0];
        const float4 y = pp[1];
        va[0] = x.x; va[1] = x.y; va[2] = x.z; va[3] = x.w;
        va[4] = y.x; va[5] = y.y; va[6] = y.z; va[7] = y.w;
      } else {
#pragma unroll
        for (int q = 0; q < 8; ++q) va[q] = dv;
      }
#pragma unroll
      for (int q = 0; q < 8; ++q) a1[q] = fcvt(va[q]);
    }
    acc1 = __builtin_amdgcn_mfma_f32_16x16x32_bf16(a1, bfrag[p], acc1, 0, 0, 0);
  }

  const int obase = pix * (NB_D * NB_F);
#pragma unroll
  for (int rr = 0; rr < 4; ++rr) {
    out[obase + (grp * 4 + rr) * NB_F + r] = acc0[rr];
    out[obase + (grp * 4 + rr + 16) * NB_F + r] = acc1[rr];
  }
}

extern "C" void kernel_launch(void* const* d_in, const int* in_sizes, int n_in,
                              void* d_out, int out_size, void* d_ws, size_t ws_size,
                              hipStream_t stream) {
  const float* img = (const float*)d_in[0];
  const int* bp = (const int*)d_in[1];
  const float* kern = (const float*)d_in[2];
  const float* dvp = (const float*)d_in[3];
  float* out = (float*)d_out;

  if (ws_size >= WS_NEED) {
    unsigned short* kb2 = (unsigned short*)d_ws;
    sconv3d_wprep<<<28, 256, 0, stream>>>(kern, kb2);
    sconv3d_roll<<<512, 256, 0, stream>>>(img, bp, kb2, dvp, out);
  } else {
    sconv3d_mfma<<<NPIX / 4, 256, 0, stream>>>(img, bp, kern, dvp, out, NPIX);
  }
}